// Round 2
// baseline (118.611 us; speedup 1.0000x reference)
//
#include <hip/hip_runtime.h>

#define NT 256

constexpr int L0 = 8192;
constexpr int N1 = 4099;   // (8192+7)>>1
constexpr int N2 = 2053;   // (4099+7)>>1
constexpr int N3 = 1030;   // (2053+7)>>1
constexpr int N4 = 518;    // (1030+7)>>1
constexpr int ROW_OUT = N4 + N4 + N3 + N2 + N1;  // 8218

// lo[i] = sum_j GLO[j] * xsym(2i-6+j)   (GLO = pywt db4 rec_lo = dec_lo reversed)
constexpr float GLO[8] = {
    0.23037781330885523f,  0.7148465705525415f,   0.6308807679295904f,
   -0.02798376941698385f, -0.18703481171888114f,  0.030841381835986965f,
    0.032883011666982945f, -0.010597401784997278f };
// hi[i] = sum_j GHI[j] * xsym(2i-6+j)   (GHI[j] = (-1)^j * rec_lo[7-j] = dec_hi reversed)
constexpr float GHI[8] = {
   -0.010597401784997278f, -0.032883011666982945f, 0.030841381835986965f,
    0.18703481171888114f,  -0.02798376941698385f,  -0.6308807679295904f,
    0.7148465705525415f,   -0.23037781330885523f };

// De-interleaved representation: a[2k]=E[k], a[2k+1]=O[k].
// Window a_sym[2i-6+j]: even j -> E[i-3+j/2], odd j -> O[i-3+(j-1)/2].
// Symmetric pads: E[-p]=O[p-1], O[-p]=E[p-1];
//                 E[nE+t]=O[n-1-nE-t], O[nO+t]=E[n-1-nO-t].
__device__ __forceinline__ void set_pads(float* __restrict__ e, float* __restrict__ o,
                                         int n, int nE, int nO, int nout, int tid)
{
    if (tid < 4) {
        if (tid < 3) {
            e[-1 - tid] = o[tid];
            o[-1 - tid] = e[tid];
        }
        if (tid < nout - nE) e[nE + tid] = o[n - 1 - nE - tid];
        if (tid < nout - nO) o[nO + tid] = e[n - 1 - nO - tid];
    }
}

// e,o: interior pointers of the level input (pads valid at [-3..] and right).
// lo goes to next level's split arrays (or global if LAST); hi goes to global.
template <bool LAST>
__device__ __forceinline__ void dwt_level_split(const float* __restrict__ e,
                                                const float* __restrict__ o,
                                                int nout,
                                                float* __restrict__ eN,
                                                float* __restrict__ oN,
                                                float* __restrict__ loG,
                                                float* __restrict__ hiG, int tid)
{
    for (int i = tid; i < nout; i += NT) {
        const float* pe = e + i - 3;
        const float* po = o + i - 3;
        float lo = 0.f, hi = 0.f;
#pragma unroll
        for (int m = 0; m < 4; ++m) {
            float ve = pe[m];
            float vo = po[m];
            lo = fmaf(GLO[2 * m], ve, lo);
            lo = fmaf(GLO[2 * m + 1], vo, lo);
            hi = fmaf(GHI[2 * m], ve, hi);
            hi = fmaf(GHI[2 * m + 1], vo, hi);
        }
        hiG[i] = hi;
        if (LAST) {
            loG[i] = lo;
        } else {
            float* t = (i & 1) ? oN : eN;   // lo[i] = next-level a[i]
            t[i >> 1] = lo;
        }
    }
}

__global__ __launch_bounds__(NT) void wavedec4_db4(const float* __restrict__ x,
                                                   float* __restrict__ out)
{
    // Ping-pong split buffers: interior starts at +4 (16B aligned), 3 left + 4 right pads.
    __shared__ __align__(16) float eA[4 + 4096 + 4], oA[4 + 4096 + 4];
    __shared__ __align__(16) float eB[4 + 2050 + 4], oB[4 + 2050 + 4];
    const int tid = threadIdx.x;
    const float* __restrict__ xr = x + blockIdx.x * (size_t)L0;
    float* __restrict__ outr = out + blockIdx.x * (size_t)ROW_OUT;
    float* E0 = eA + 4; float* O0 = oA + 4;
    float* E1 = eB + 4; float* O1 = oB + 4;

    // Stage row, de-interleaved: float4 -> (x,z) evens, (y,w) odds via float2 LDS stores.
    const float4* x4 = (const float4*)xr;
    float2* e2 = (float2*)E0;
    float2* o2 = (float2*)O0;
    for (int idx = tid; idx < L0 / 4; idx += NT) {
        float4 v = x4[idx];
        e2[idx] = make_float2(v.x, v.z);
        o2[idx] = make_float2(v.y, v.w);
    }
    __syncthreads();
    set_pads(E0, O0, L0, 4096, 4096, N1, tid);
    __syncthreads();

    // L1: (E0,O0) n=8192 -> (E1,O1); cD1 -> out[4119..)
    dwt_level_split<false>(E0, O0, N1, E1, O1, nullptr, outr + (N4 + N4 + N3 + N2), tid);
    __syncthreads();
    set_pads(E1, O1, N1, 2050, 2049, N2, tid);
    __syncthreads();

    // L2: (E1,O1) n=4099 -> (E0,O0); cD2 -> out[2066..)
    dwt_level_split<false>(E1, O1, N2, E0, O0, nullptr, outr + (N4 + N4 + N3), tid);
    __syncthreads();
    set_pads(E0, O0, N2, 1027, 1026, N3, tid);
    __syncthreads();

    // L3: (E0,O0) n=2053 -> (E1,O1); cD3 -> out[1036..)
    dwt_level_split<false>(E0, O0, N3, E1, O1, nullptr, outr + (N4 + N4), tid);
    __syncthreads();
    set_pads(E1, O1, N3, 515, 515, N4, tid);
    __syncthreads();

    // L4: (E1,O1) n=1030 -> cA4 = out[0..518), cD4 = out[518..1036)
    dwt_level_split<true>(E1, O1, N4, nullptr, nullptr, outr, outr + N4, tid);
}

extern "C" void kernel_launch(void* const* d_in, const int* in_sizes, int n_in,
                              void* d_out, int out_size, void* d_ws, size_t ws_size,
                              hipStream_t stream) {
    const float* x = (const float*)d_in[0];
    float* out = (float*)d_out;
    const int rows = in_sizes[0] / L0;  // 64*32 = 2048
    wavedec4_db4<<<dim3(rows), dim3(NT), 0, stream>>>(x, out);
}